// Round 11
// baseline (341.359 us; speedup 1.0000x reference)
//
#include <hip/hip_runtime.h>
#include <stdint.h>
#include <stddef.h>

#define MM 512
#define NN 512
#define EE 256
#define HH 16
#define DD 16

// Diagnostic rep counts (idempotent re-execution; output identical).
#define REPS_P 6
#define REPS_A 2
#define REPS_O 10

typedef __bf16 bf16x8 __attribute__((ext_vector_type(8)));
typedef float f32x4 __attribute__((ext_vector_type(4)));

static __device__ __forceinline__ bf16x8 bzero8() {
  bf16x8 z;
#pragma unroll
  for (int i = 0; i < 8; ++i) z[i] = (__bf16)0.0f;
  return z;
}

static __device__ __forceinline__ bf16x8 cvt8(const float* __restrict__ p) {
  const float4 u = *(const float4*)p;
  const float4 v = *(const float4*)(p + 4);
  bf16x8 r;
  r[0] = (__bf16)u.x; r[1] = (__bf16)u.y; r[2] = (__bf16)u.z; r[3] = (__bf16)u.w;
  r[4] = (__bf16)v.x; r[5] = (__bf16)v.y; r[6] = (__bf16)v.z; r[7] = (__bf16)v.w;
  return r;
}

static __device__ __forceinline__ unsigned short f2b(float f) {
  union { __bf16 h; unsigned short u; } cv;
  cv.h = (__bf16)f;
  return cv.u;
}

static __device__ __forceinline__ float b2f(unsigned short u) {
  union { unsigned int i; float f; } cv;
  cv.i = ((unsigned int)u) << 16;
  return cv.f;
}

static __device__ __forceinline__ float fexp2(float x) {
  float r;
  asm("v_exp_f32 %0, %1" : "=v"(r) : "v"(x));
  return r;
}

static __device__ __forceinline__ unsigned int cvtpk(float lo, float hi) {
  unsigned int r;
  asm("v_cvt_pk_bf16_f32 %0, %1, %2" : "=v"(r) : "v"(lo), "v"(hi));
  return r;
}

static __device__ __forceinline__ float sload(const float* p) {
  return __int_as_float(__builtin_amdgcn_readfirstlane(__float_as_int(*p)));
}

// ---------------------------------------------------------------------------
// Kernel 1: projections (round-2 body), DIAGNOSTIC x REPS_P
// ---------------------------------------------------------------------------
__global__ __launch_bounds__(256) void proj_all_kernel(
    const float* __restrict__ Xq, const float* __restrict__ Xkv,
    const float* __restrict__ Wq, const float* __restrict__ Wkv,
    const float* __restrict__ Wout,
    unsigned short* __restrict__ Qs, unsigned short* __restrict__ Ks,
    unsigned short* __restrict__ Vt,
    unsigned short* __restrict__ Whi, unsigned short* __restrict__ Wlo) {
  const int by = blockIdx.y;
  const int tid = threadIdx.x;
  const int w = tid >> 6, l = tid & 63;
  const int lg = l >> 4, lr = l & 15;
  const int t0 = blockIdx.x * 32 + (w & 1) * 16;

#pragma clang loop unroll(disable)
  for (int rep = 0; rep < REPS_P; ++rep) {
    if (by == 12) {
      const int base = (blockIdx.x * 256 + tid) * 4;
      const float4 v = *(const float4*)(Wout + base);
      float c4[4] = {v.x, v.y, v.z, v.w};
#pragma unroll
      for (int i = 0; i < 4; ++i) {
        const unsigned short hb = f2b(c4[i]);
        Whi[base + i] = hb;
        Wlo[base + i] = f2b(c4[i] - b2f(hb));
      }
    } else if (by < 4) {
      const int n0 = by * 64 + (w >> 1) * 32;
      f32x4 acc0 = {0.f, 0.f, 0.f, 0.f}, acc1 = {0.f, 0.f, 0.f, 0.f};
#pragma unroll
      for (int kc = 0; kc < EE; kc += 32) {
        const int k = kc + lg * 8;
        bf16x8 a  = cvt8(Xq + (size_t)(t0 + lr) * EE + k);
        bf16x8 b0 = cvt8(Wq + (size_t)(n0 + lr) * EE + k);
        bf16x8 b1 = cvt8(Wq + (size_t)(n0 + 16 + lr) * EE + k);
        acc0 = __builtin_amdgcn_mfma_f32_16x16x32_bf16(a, b0, acc0, 0, 0, 0);
        acc1 = __builtin_amdgcn_mfma_f32_16x16x32_bf16(a, b1, acc1, 0, 0, 0);
      }
#pragma unroll
      for (int r = 0; r < 4; ++r) {
        const int t = t0 + 4 * lg + r, b = t >> 9, m = t & 511;
        const int j0 = n0 + lr, j1 = j0 + 16;
        Qs[((size_t)(b * HH + (j0 >> 4)) * MM + m) * DD + (j0 & 15)] = f2b(acc0[r] * 0.25f);
        Qs[((size_t)(b * HH + (j1 >> 4)) * MM + m) * DD + (j1 & 15)] = f2b(acc1[r] * 0.25f);
      }
    } else {
      const int n0 = (by - 4) * 64 + (w >> 1) * 32;
      f32x4 acc0 = {0.f, 0.f, 0.f, 0.f}, acc1 = {0.f, 0.f, 0.f, 0.f};
#pragma unroll
      for (int kc = 0; kc < EE; kc += 32) {
        const int k = kc + lg * 8;
        bf16x8 a  = cvt8(Xkv + (size_t)(t0 + lr) * EE + k);
        bf16x8 b0 = cvt8(Wkv + (size_t)(n0 + lr) * EE + k);
        bf16x8 b1 = cvt8(Wkv + (size_t)(n0 + 16 + lr) * EE + k);
        acc0 = __builtin_amdgcn_mfma_f32_16x16x32_bf16(a, b0, acc0, 0, 0, 0);
        acc1 = __builtin_amdgcn_mfma_f32_16x16x32_bf16(a, b1, acc1, 0, 0, 0);
      }
#pragma unroll
      for (int r = 0; r < 4; ++r) {
        const int t = t0 + 4 * lg + r, b = t >> 9, n = t & 511;
#pragma unroll
        for (int fi = 0; fi < 2; ++fi) {
          const int j = n0 + lr + fi * 16;
          const float v = fi ? acc1[r] : acc0[r];
          if (j < 256) {
            Ks[((size_t)(b * HH + (j >> 4)) * NN + n) * DD + (j & 15)] = f2b(v);
          } else {
            const int jj = j - 256;
            Vt[((size_t)(b * HH + (jj >> 4)) * DD + (jj & 15)) * NN + n] = f2b(v);
          }
        }
      }
    }
  }
}

// ---------------------------------------------------------------------------
// Kernel 2: fused attention (round-10 body incl. XCD swizzle + prefetch),
// DIAGNOSTIC x REPS_A
// ---------------------------------------------------------------------------
__global__ __launch_bounds__(256, 2) void attn_kernel(
    const unsigned short* __restrict__ Qs, const unsigned short* __restrict__ Ks,
    const unsigned short* __restrict__ Vt, const float* __restrict__ dmat,
    const float* __restrict__ W1, const float* __restrict__ b1v,
    const float* __restrict__ W2,
    unsigned short* __restrict__ Ahi, unsigned short* __restrict__ Alo) {
  __shared__ unsigned short P[32][520];
  __shared__ float red[4][32];
  float (*pvred)[2][16][16] = (float (*)[2][16][16]) & P[0][0];  // 8KB alias

  const int tid = threadIdx.x, w = tid >> 6, l = tid & 63;
  const int lg = l >> 4, lr = l & 15;
  const int bid = blockIdx.x;
  const int xcd = bid & 7, slot = bid >> 3;
  const int b = xcd >> 1;
  const int idx = ((xcd & 1) << 7) | slot;
  const int hh = idx >> 4, mt = idx & 15;
  const int m0 = mt * 32;
  const int n0 = w * 128;

  const unsigned short* Qbase = Qs + ((size_t)(b * HH + hh) * MM + m0) * DD;
  const unsigned short* Kbase = Ks + (size_t)(b * HH + hh) * NN * DD;
  const unsigned short* Vbase = Vt + (size_t)(b * HH + hh) * DD * NN;
  const float* dbase = dmat + (size_t)b * MM * NN;

  float ckv[16], bkv[16], wkp[16];
  float Ac = 0.f, Cc = 0.f;
  const float hiln2 = 0.5f * 1.4426950408889634f;
#pragma unroll
  for (int k = 0; k < 16; ++k) {
    const float ak = sload(W1 + hh * 32 + k);
    const float ck = sload(W1 + hh * 32 + 16 + k);
    const float bk = sload(b1v + hh * 16 + k);
    const float wk = hiln2 * sload(W2 + hh * 16 + k);
    Ac += wk * ak;
    Cc += wk * ck;
    const float ra = 1.0f / ak;
    ckv[k] = ck * ra;
    bkv[k] = bk * ra;
    wkp[k] = wk * fabsf(ak);
    asm volatile("" : "+v"(ckv[k]));
    asm volatile("" : "+v"(bkv[k]));
  }

  const f32x4 zf = {0.f, 0.f, 0.f, 0.f};
  const float* dpl0 = dbase + (size_t)(m0 + lr) * NN + n0 + 4 * lg;
  const float* dpl1 = dbase + (size_t)(m0 + 16 + lr) * NN + n0 + 4 * lg;

#pragma clang loop unroll(disable)
  for (int rep = 0; rep < REPS_A; ++rep) {
    __syncthreads();   // protect P from prior rep's aliased pvred reads

    bf16x8 qb[2];
#pragma unroll
    for (int mb = 0; mb < 2; ++mb) {
      qb[mb] = bzero8();
      if (lg < 2) qb[mb] = *(const bf16x8*)(Qbase + (mb * 16 + lr) * DD + lg * 8);
    }

    float psum[2] = {0.f, 0.f};

    float4 dva0 = *(const float4*)(dpl0);
    float4 dva1 = *(const float4*)(dpl1);
    bf16x8 ka0 = bzero8();
    if (lg < 2) ka0 = *(const bf16x8*)(Kbase + (size_t)(n0 + lr) * DD + lg * 8);

#pragma unroll
    for (int nb = 0; nb < 8; ++nb) {
      float4 dvb0, dvb1;
      bf16x8 ka1 = bzero8();
      if (nb < 7) {
        dvb0 = *(const float4*)(dpl0 + (nb + 1) * 16);
        dvb1 = *(const float4*)(dpl1 + (nb + 1) * 16);
        if (lg < 2)
          ka1 = *(const bf16x8*)(Kbase + (size_t)(n0 + (nb + 1) * 16 + lr) * DD + lg * 8);
      }

      f32x4 cc[2];
      cc[0] = __builtin_amdgcn_mfma_f32_16x16x32_bf16(ka0, qb[0], zf, 0, 0, 0);
      cc[1] = __builtin_amdgcn_mfma_f32_16x16x32_bf16(ka0, qb[1], zf, 0, 0, 0);

#pragma unroll
      for (int mb = 0; mb < 2; ++mb) {
        const float4 dvv = mb ? dva1 : dva0;
        float ev[4];
#pragma unroll
        for (int r = 0; r < 4; ++r) {
          const float s = cc[mb][r];
          const float d = (r == 0) ? dvv.x : (r == 1) ? dvv.y : (r == 2) ? dvv.z : dvv.w;
          float acc = fmaf(Ac, s, Cc * d);
#pragma unroll
          for (int k = 0; k < 16; ++k) {
            const float t = fmaf(ckv[k], d, bkv[k]);
            acc = fmaf(wkp[k], fabsf(s + t), acc);
          }
          const float e = fexp2(acc);
          psum[mb] += e;
          ev[r] = e;
        }
        uint2 u;
        u.x = cvtpk(ev[0], ev[1]);
        u.y = cvtpk(ev[2], ev[3]);
        *(uint2*)&P[mb * 16 + lr][n0 + nb * 16 + 4 * lg] = u;
      }

      dva0 = dvb0;
      dva1 = dvb1;
      ka0 = ka1;
    }

#pragma unroll
    for (int mb = 0; mb < 2; ++mb) {
      psum[mb] += __shfl_xor(psum[mb], 16);
      psum[mb] += __shfl_xor(psum[mb], 32);
      if (lg == 0) red[w][mb * 16 + lr] = psum[mb];
    }

    f32x4 pv[2];
    pv[0] = zf; pv[1] = zf;
#pragma unroll
    for (int kb = 0; kb < 4; ++kb) {
      const bf16x8 vb = *(const bf16x8*)(Vbase + (size_t)lr * NN + (n0 + kb * 32 + lg * 8));
#pragma unroll
      for (int mb = 0; mb < 2; ++mb) {
        const bf16x8 pa = *(const bf16x8*)(&P[mb * 16 + lr][n0 + kb * 32 + lg * 8]);
        pv[mb] = __builtin_amdgcn_mfma_f32_16x16x32_bf16(pa, vb, pv[mb], 0, 0, 0);
      }
    }
    __syncthreads();
#pragma unroll
    for (int mb = 0; mb < 2; ++mb)
#pragma unroll
      for (int r = 0; r < 4; ++r) pvred[w][mb][4 * lg + r][lr] = pv[mb][r];
    __syncthreads();

    for (int i = tid; i < 512; i += 256) {
      const int mr = i >> 4, dd = i & 15;
      const float s = pvred[0][mr >> 4][mr & 15][dd] + pvred[1][mr >> 4][mr & 15][dd] +
                      pvred[2][mr >> 4][mr & 15][dd] + pvred[3][mr >> 4][mr & 15][dd];
      const float rs = red[0][mr] + red[1][mr] + red[2][mr] + red[3][mr];
      const float val = s / rs;
      const unsigned short hb = f2b(val);
      const size_t o = ((size_t)(b * MM) + m0 + mr) * EE + hh * DD + dd;
      Ahi[o] = hb;
      Alo[o] = f2b(val - b2f(hb));
    }
  }
}

// ---------------------------------------------------------------------------
// Kernel 3: out GEMM (round-2 body), DIAGNOSTIC x REPS_O
// ---------------------------------------------------------------------------
__global__ __launch_bounds__(256) void out_gemm_kernel(
    const unsigned short* __restrict__ Ahi, const unsigned short* __restrict__ Alo,
    const unsigned short* __restrict__ Whi, const unsigned short* __restrict__ Wlo,
    float* __restrict__ out) {
  const int tid = threadIdx.x, w = tid >> 6, l = tid & 63;
  const int lg = l >> 4, lr = l & 15;
  const int t0 = blockIdx.x * 32 + (w & 1) * 16;
  const int n0 = blockIdx.y * 64 + (w >> 1) * 32;

#pragma clang loop unroll(disable)
  for (int rep = 0; rep < REPS_O; ++rep) {
    f32x4 acc0 = {0.f, 0.f, 0.f, 0.f}, acc1 = {0.f, 0.f, 0.f, 0.f};
#pragma unroll
    for (int kc = 0; kc < EE; kc += 32) {
      const int k = kc + lg * 8;
      const bf16x8 ah = *(const bf16x8*)(Ahi + (size_t)(t0 + lr) * EE + k);
      const bf16x8 al = *(const bf16x8*)(Alo + (size_t)(t0 + lr) * EE + k);
      const bf16x8 bh0 = *(const bf16x8*)(Whi + (size_t)(n0 + lr) * EE + k);
      const bf16x8 bh1 = *(const bf16x8*)(Whi + (size_t)(n0 + 16 + lr) * EE + k);
      const bf16x8 bl0 = *(const bf16x8*)(Wlo + (size_t)(n0 + lr) * EE + k);
      const bf16x8 bl1 = *(const bf16x8*)(Wlo + (size_t)(n0 + 16 + lr) * EE + k);
      acc0 = __builtin_amdgcn_mfma_f32_16x16x32_bf16(ah, bh0, acc0, 0, 0, 0);
      acc0 = __builtin_amdgcn_mfma_f32_16x16x32_bf16(al, bh0, acc0, 0, 0, 0);
      acc0 = __builtin_amdgcn_mfma_f32_16x16x32_bf16(ah, bl0, acc0, 0, 0, 0);
      acc1 = __builtin_amdgcn_mfma_f32_16x16x32_bf16(ah, bh1, acc1, 0, 0, 0);
      acc1 = __builtin_amdgcn_mfma_f32_16x16x32_bf16(al, bh1, acc1, 0, 0, 0);
      acc1 = __builtin_amdgcn_mfma_f32_16x16x32_bf16(ah, bl1, acc1, 0, 0, 0);
    }
#pragma unroll
    for (int r = 0; r < 4; ++r) {
      const int row = t0 + 4 * lg + r;
      out[(size_t)row * EE + n0 + lr] = acc0[r];
      out[(size_t)row * EE + n0 + 16 + lr] = acc1[r];
    }
  }
}

// ---------------------------------------------------------------------------
extern "C" void kernel_launch(void* const* d_in, const int* in_sizes, int n_in,
                              void* d_out, int out_size, void* d_ws, size_t ws_size,
                              hipStream_t stream) {
  const float* q_input  = (const float*)d_in[0];
  const float* kv_input = (const float*)d_in[1];
  const float* dmat     = (const float*)d_in[2];
  const float* Wq       = (const float*)d_in[3];
  const float* Wkv      = (const float*)d_in[4];
  const float* W1       = (const float*)d_in[5];
  const float* b1       = (const float*)d_in[6];
  const float* W2       = (const float*)d_in[7];
  // d_in[8] = mix_b2: no effect inside softmax, unused
  const float* Wout     = (const float*)d_in[9];
  float* out = (float*)d_out;

  char* ws = (char*)d_ws;
  unsigned short* Qs  = (unsigned short*)(ws);
  unsigned short* Ks  = (unsigned short*)(ws + (1u << 20));
  unsigned short* Vt  = (unsigned short*)(ws + (2u << 20));
  unsigned short* Ahi = (unsigned short*)(ws + (3u << 20));
  unsigned short* Alo = (unsigned short*)(ws + (4u << 20));
  unsigned short* Whi = (unsigned short*)(ws + (5u << 20));
  unsigned short* Wlo = (unsigned short*)(ws + (5u << 20) + (1u << 17));

  proj_all_kernel<<<dim3(64, 13), 256, 0, stream>>>(q_input, kv_input, Wq, Wkv, Wout,
                                                    Qs, Ks, Vt, Whi, Wlo);
  attn_kernel<<<dim3(1024), 256, 0, stream>>>(Qs, Ks, Vt, dmat, W1, b1, W2,
                                              Ahi, Alo);
  out_gemm_kernel<<<dim3(64, 4), 256, 0, stream>>>(Ahi, Alo, Whi, Wlo, out);
}

// Round 12
// 173.391 us; speedup vs baseline: 1.9687x; 1.9687x over previous
//
#include <hip/hip_runtime.h>
#include <stdint.h>
#include <stddef.h>

#define MM 512
#define NN 512
#define EE 256
#define HH 16
#define DD 16

typedef __bf16 bf16x8 __attribute__((ext_vector_type(8)));
typedef float f32x4 __attribute__((ext_vector_type(4)));

static __device__ __forceinline__ bf16x8 bzero8() {
  bf16x8 z;
#pragma unroll
  for (int i = 0; i < 8; ++i) z[i] = (__bf16)0.0f;
  return z;
}

static __device__ __forceinline__ bf16x8 cvt8(const float* __restrict__ p) {
  const float4 u = *(const float4*)p;
  const float4 v = *(const float4*)(p + 4);
  bf16x8 r;
  r[0] = (__bf16)u.x; r[1] = (__bf16)u.y; r[2] = (__bf16)u.z; r[3] = (__bf16)u.w;
  r[4] = (__bf16)v.x; r[5] = (__bf16)v.y; r[6] = (__bf16)v.z; r[7] = (__bf16)v.w;
  return r;
}

static __device__ __forceinline__ unsigned short f2b(float f) {
  union { __bf16 h; unsigned short u; } cv;
  cv.h = (__bf16)f;
  return cv.u;
}

static __device__ __forceinline__ float b2f(unsigned short u) {
  union { unsigned int i; float f; } cv;
  cv.i = ((unsigned int)u) << 16;
  return cv.f;
}

// raw v_exp_f32: computes 2^x (1/ln2 folded into MLP coefficients)
static __device__ __forceinline__ float fexp2(float x) {
  float r;
  asm("v_exp_f32 %0, %1" : "=v"(r) : "v"(x));
  return r;
}

// packed bf16 convert: dst.lo = bf16(lo), dst.hi = bf16(hi)
static __device__ __forceinline__ unsigned int cvtpk(float lo, float hi) {
  unsigned int r;
  asm("v_cvt_pk_bf16_f32 %0, %1, %2" : "=v"(r) : "v"(lo), "v"(hi));
  return r;
}

static __device__ __forceinline__ float sload(const float* p) {
  return __int_as_float(__builtin_amdgcn_readfirstlane(__float_as_int(*p)));
}

// ---------------------------------------------------------------------------
// Kernel 1: projections. by 0-3 -> Q, 4-11 -> KV, 12 -> Wout split + cnt zero
// ---------------------------------------------------------------------------
__global__ __launch_bounds__(256) void proj_all_kernel(
    const float* __restrict__ Xq, const float* __restrict__ Xkv,
    const float* __restrict__ Wq, const float* __restrict__ Wkv,
    const float* __restrict__ Wout,
    unsigned short* __restrict__ Qs, unsigned short* __restrict__ Ks,
    unsigned short* __restrict__ Vt,
    unsigned short* __restrict__ Whi, unsigned short* __restrict__ Wlo,
    unsigned int* __restrict__ cnt) {
  const int by = blockIdx.y;
  const int tid = threadIdx.x;

  if (by == 12) {
    if (blockIdx.x == 0 && tid < 64) cnt[tid] = 0u;  // tail counters, each call
    const int base = (blockIdx.x * 256 + tid) * 4;
    const float4 v = *(const float4*)(Wout + base);
    float c4[4] = {v.x, v.y, v.z, v.w};
#pragma unroll
    for (int i = 0; i < 4; ++i) {
      const unsigned short hb = f2b(c4[i]);
      Whi[base + i] = hb;
      Wlo[base + i] = f2b(c4[i] - b2f(hb));
    }
    return;
  }

  const int w = tid >> 6, l = tid & 63;
  const int lg = l >> 4, lr = l & 15;
  const int t0 = blockIdx.x * 32 + (w & 1) * 16;

  if (by < 4) {
    const int n0 = by * 64 + (w >> 1) * 32;
    f32x4 acc0 = {0.f, 0.f, 0.f, 0.f}, acc1 = {0.f, 0.f, 0.f, 0.f};
#pragma unroll
    for (int kc = 0; kc < EE; kc += 32) {
      const int k = kc + lg * 8;
      bf16x8 a  = cvt8(Xq + (size_t)(t0 + lr) * EE + k);
      bf16x8 b0 = cvt8(Wq + (size_t)(n0 + lr) * EE + k);
      bf16x8 b1 = cvt8(Wq + (size_t)(n0 + 16 + lr) * EE + k);
      acc0 = __builtin_amdgcn_mfma_f32_16x16x32_bf16(a, b0, acc0, 0, 0, 0);
      acc1 = __builtin_amdgcn_mfma_f32_16x16x32_bf16(a, b1, acc1, 0, 0, 0);
    }
#pragma unroll
    for (int r = 0; r < 4; ++r) {
      const int t = t0 + 4 * lg + r, b = t >> 9, m = t & 511;
      const int j0 = n0 + lr, j1 = j0 + 16;
      Qs[((size_t)(b * HH + (j0 >> 4)) * MM + m) * DD + (j0 & 15)] = f2b(acc0[r] * 0.25f);
      Qs[((size_t)(b * HH + (j1 >> 4)) * MM + m) * DD + (j1 & 15)] = f2b(acc1[r] * 0.25f);
    }
  } else {
    const int n0 = (by - 4) * 64 + (w >> 1) * 32;
    f32x4 acc0 = {0.f, 0.f, 0.f, 0.f}, acc1 = {0.f, 0.f, 0.f, 0.f};
#pragma unroll
    for (int kc = 0; kc < EE; kc += 32) {
      const int k = kc + lg * 8;
      bf16x8 a  = cvt8(Xkv + (size_t)(t0 + lr) * EE + k);
      bf16x8 b0 = cvt8(Wkv + (size_t)(n0 + lr) * EE + k);
      bf16x8 b1 = cvt8(Wkv + (size_t)(n0 + 16 + lr) * EE + k);
      acc0 = __builtin_amdgcn_mfma_f32_16x16x32_bf16(a, b0, acc0, 0, 0, 0);
      acc1 = __builtin_amdgcn_mfma_f32_16x16x32_bf16(a, b1, acc1, 0, 0, 0);
    }
#pragma unroll
    for (int r = 0; r < 4; ++r) {
      const int t = t0 + 4 * lg + r, b = t >> 9, n = t & 511;
#pragma unroll
      for (int fi = 0; fi < 2; ++fi) {
        const int j = n0 + lr + fi * 16;
        const float v = fi ? acc1[r] : acc0[r];
        if (j < 256) {
          Ks[((size_t)(b * HH + (j >> 4)) * NN + n) * DD + (j & 15)] = f2b(v);
        } else {
          const int jj = j - 256;
          Vt[((size_t)(b * HH + (jj >> 4)) * DD + (jj & 15)) * NN + n] = f2b(v);
        }
      }
    }
  }
}

// ---------------------------------------------------------------------------
// Kernel 2: fused attention (round-10 body) + last-sibling out-GEMM tail.
// Sibling-group XCD swizzle: group g=(b*16+mt) -> XCD g&7; all 16 head-blocks
// of a group share that XCD's L2 (64KB dmat tile fetched once; Ahi/Alo for
// the tail stay L2-local). bid = slot*8 + (g&7), slot = (g>>3)*16 + h.
// ---------------------------------------------------------------------------
__global__ __launch_bounds__(256, 4) void attn_kernel(
    const unsigned short* __restrict__ Qs, const unsigned short* __restrict__ Ks,
    const unsigned short* __restrict__ Vt, const float* __restrict__ dmat,
    const float* __restrict__ W1, const float* __restrict__ b1v,
    const float* __restrict__ W2,
    unsigned short* __restrict__ Ahi, unsigned short* __restrict__ Alo,
    const unsigned short* __restrict__ Whi, const unsigned short* __restrict__ Wlo,
    float* __restrict__ out, unsigned int* __restrict__ cnt) {
  __shared__ unsigned short P[32][520];   // bf16 probs; pvred aliased later
  __shared__ float red[4][32];            // per-wave row sums
  __shared__ int lastf;
  float (*pvred)[2][16][16] = (float (*)[2][16][16]) & P[0][0];  // 8KB alias

  const int tid = threadIdx.x, w = tid >> 6, l = tid & 63;
  const int lg = l >> 4, lr = l & 15;
  const int bid = blockIdx.x;
  // decode sibling-group swizzle
  const int xcd = bid & 7, slot = bid >> 3;
  const int hh = slot & 15;
  const int g = (slot >> 4) * 8 + xcd;      // 0..63
  const int b = g >> 4, mt = g & 15;
  const int m0 = mt * 32;
  const int n0 = w * 128;

  const unsigned short* Qbase = Qs + ((size_t)(b * HH + hh) * MM + m0) * DD;
  const unsigned short* Kbase = Ks + (size_t)(b * HH + hh) * NN * DD;
  const unsigned short* Vbase = Vt + (size_t)(b * HH + hh) * DD * NN;
  const float* dbase = dmat + (size_t)b * MM * NN;

  // MLP coefficients. relu(x)=(x+|x|)/2, fold 0.5*W2 and 1/ln2 into wk;
  // wk|ak s + ck d + bk| = wkp*|s + ckp*d + bkp|. ckv/bkv pinned to VGPRs.
  float ckv[16], bkv[16], wkp[16];
  float Ac = 0.f, Cc = 0.f;
  const float hiln2 = 0.5f * 1.4426950408889634f;
#pragma unroll
  for (int k = 0; k < 16; ++k) {
    const float ak = sload(W1 + hh * 32 + k);
    const float ck = sload(W1 + hh * 32 + 16 + k);
    const float bk = sload(b1v + hh * 16 + k);
    const float wk = hiln2 * sload(W2 + hh * 16 + k);
    Ac += wk * ak;
    Cc += wk * ck;
    const float ra = 1.0f / ak;
    ckv[k] = ck * ra;
    bkv[k] = bk * ra;
    wkp[k] = wk * fabsf(ak);
    asm volatile("" : "+v"(ckv[k]));
    asm volatile("" : "+v"(bkv[k]));
  }

  bf16x8 qb[2];
#pragma unroll
  for (int mb = 0; mb < 2; ++mb) {
    qb[mb] = bzero8();
    if (lg < 2) qb[mb] = *(const bf16x8*)(Qbase + (mb * 16 + lr) * DD + lg * 8);
  }

  const f32x4 zf = {0.f, 0.f, 0.f, 0.f};
  float psum[2] = {0.f, 0.f};

  const float* dpl0 = dbase + (size_t)(m0 + lr) * NN + n0 + 4 * lg;
  const float* dpl1 = dbase + (size_t)(m0 + 16 + lr) * NN + n0 + 4 * lg;

  float4 dva0 = *(const float4*)(dpl0);
  float4 dva1 = *(const float4*)(dpl1);
  bf16x8 ka0 = bzero8();
  if (lg < 2) ka0 = *(const bf16x8*)(Kbase + (size_t)(n0 + lr) * DD + lg * 8);

#pragma unroll
  for (int nb = 0; nb < 8; ++nb) {
    float4 dvb0, dvb1;
    bf16x8 ka1 = bzero8();
    if (nb < 7) {
      dvb0 = *(const float4*)(dpl0 + (nb + 1) * 16);
      dvb1 = *(const float4*)(dpl1 + (nb + 1) * 16);
      if (lg < 2)
        ka1 = *(const bf16x8*)(Kbase + (size_t)(n0 + (nb + 1) * 16 + lr) * DD + lg * 8);
    }

    // swapped QK^T: C = S^T, row = n (4lg+r), col = m (lr)
    f32x4 cc[2];
    cc[0] = __builtin_amdgcn_mfma_f32_16x16x32_bf16(ka0, qb[0], zf, 0, 0, 0);
    cc[1] = __builtin_amdgcn_mfma_f32_16x16x32_bf16(ka0, qb[1], zf, 0, 0, 0);

#pragma unroll
    for (int mb = 0; mb < 2; ++mb) {
      const float4 dvv = mb ? dva1 : dva0;
      float ev[4];
#pragma unroll
      for (int r = 0; r < 4; ++r) {
        const float s = cc[mb][r];
        const float d = (r == 0) ? dvv.x : (r == 1) ? dvv.y : (r == 2) ? dvv.z : dvv.w;
        float acc = fmaf(Ac, s, Cc * d);
#pragma unroll
        for (int k = 0; k < 16; ++k) {
          const float t = fmaf(ckv[k], d, bkv[k]);
          acc = fmaf(wkp[k], fabsf(s + t), acc);
        }
        const float e = fexp2(acc);   // no max-subtraction: |mixed| bounded
        psum[mb] += e;
        ev[r] = e;
      }
      uint2 u;
      u.x = cvtpk(ev[0], ev[1]);
      u.y = cvtpk(ev[2], ev[3]);
      *(uint2*)&P[mb * 16 + lr][n0 + nb * 16 + 4 * lg] = u;
    }

    dva0 = dvb0;
    dva1 = dvb1;
    ka0 = ka1;
  }

#pragma unroll
  for (int mb = 0; mb < 2; ++mb) {
    psum[mb] += __shfl_xor(psum[mb], 16);
    psum[mb] += __shfl_xor(psum[mb], 32);
    if (lg == 0) red[w][mb * 16 + lr] = psum[mb];
  }

  // PV over this wave's own n-range (self-written P rows)
  f32x4 pv[2];
  pv[0] = zf; pv[1] = zf;
#pragma unroll
  for (int kb = 0; kb < 4; ++kb) {
    const bf16x8 vb = *(const bf16x8*)(Vbase + (size_t)lr * NN + (n0 + kb * 32 + lg * 8));
#pragma unroll
    for (int mb = 0; mb < 2; ++mb) {
      const bf16x8 pa = *(const bf16x8*)(&P[mb * 16 + lr][n0 + kb * 32 + lg * 8]);
      pv[mb] = __builtin_amdgcn_mfma_f32_16x16x32_bf16(pa, vb, pv[mb], 0, 0, 0);
    }
  }
  __syncthreads();   // all P reads complete before pvred aliases onto P
#pragma unroll
  for (int mb = 0; mb < 2; ++mb)
#pragma unroll
    for (int r = 0; r < 4; ++r) pvred[w][mb][4 * lg + r][lr] = pv[mb][r];
  __syncthreads();

  for (int i = tid; i < 512; i += 256) {
    const int mr = i >> 4, dd = i & 15;
    const float s = pvred[0][mr >> 4][mr & 15][dd] + pvred[1][mr >> 4][mr & 15][dd] +
                    pvred[2][mr >> 4][mr & 15][dd] + pvred[3][mr >> 4][mr & 15][dd];
    const float rs = red[0][mr] + red[1][mr] + red[2][mr] + red[3][mr];
    const float val = s / rs;
    const unsigned short hb = f2b(val);
    const size_t o = ((size_t)(b * MM) + m0 + mr) * EE + hh * DD + dd;
    Ahi[o] = hb;
    Alo[o] = f2b(val - b2f(hb));
  }

  // ---- last of the 16 head-siblings computes out = A @ Wout^T for (b,mt) ----
  if (tid == 0) {
    __threadfence();   // release this block's Ahi/Alo stores
    const unsigned int old = __hip_atomic_fetch_add(
        &cnt[g], 1u, __ATOMIC_ACQ_REL, __HIP_MEMORY_SCOPE_AGENT);
    lastf = (old == 15u) ? 1 : 0;
  }
  __syncthreads();
  if (lastf) {
    __threadfence();   // acquire side
    // wave w: rows (w&1)*16 of the 32-row tile, cols (w>>1)*128 of 256
    const int rbase = b * MM + m0 + (w & 1) * 16;
    const int c0 = (w >> 1) * 128;
    f32x4 acc[8] = {zf, zf, zf, zf, zf, zf, zf, zf};
#pragma unroll
    for (int kc = 0; kc < EE; kc += 32) {
      const int k = kc + lg * 8;
      const bf16x8 ah = *(const bf16x8*)(Ahi + (size_t)(rbase + lr) * EE + k);
      const bf16x8 al = *(const bf16x8*)(Alo + (size_t)(rbase + lr) * EE + k);
#pragma unroll
      for (int t = 0; t < 8; ++t) {
        const bf16x8 bh = *(const bf16x8*)(Whi + (size_t)(c0 + t * 16 + lr) * EE + k);
        const bf16x8 bl = *(const bf16x8*)(Wlo + (size_t)(c0 + t * 16 + lr) * EE + k);
        acc[t] = __builtin_amdgcn_mfma_f32_16x16x32_bf16(ah, bh, acc[t], 0, 0, 0);
        acc[t] = __builtin_amdgcn_mfma_f32_16x16x32_bf16(al, bh, acc[t], 0, 0, 0);
        acc[t] = __builtin_amdgcn_mfma_f32_16x16x32_bf16(ah, bl, acc[t], 0, 0, 0);
      }
    }
#pragma unroll
    for (int t = 0; t < 8; ++t)
#pragma unroll
      for (int r = 0; r < 4; ++r)
        out[(size_t)(rbase + 4 * lg + r) * EE + c0 + t * 16 + lr] = acc[t][r];
  }
}

// ---------------------------------------------------------------------------
extern "C" void kernel_launch(void* const* d_in, const int* in_sizes, int n_in,
                              void* d_out, int out_size, void* d_ws, size_t ws_size,
                              hipStream_t stream) {
  const float* q_input  = (const float*)d_in[0];
  const float* kv_input = (const float*)d_in[1];
  const float* dmat     = (const float*)d_in[2];
  const float* Wq       = (const float*)d_in[3];
  const float* Wkv      = (const float*)d_in[4];
  const float* W1       = (const float*)d_in[5];
  const float* b1       = (const float*)d_in[6];
  const float* W2       = (const float*)d_in[7];
  // d_in[8] = mix_b2: no effect inside softmax, unused
  const float* Wout     = (const float*)d_in[9];
  float* out = (float*)d_out;

  char* ws = (char*)d_ws;
  unsigned short* Qs  = (unsigned short*)(ws);                        // 1 MB bf16 [B][H][M][D]
  unsigned short* Ks  = (unsigned short*)(ws + (1u << 20));           // 1 MB bf16 [B][H][N][D]
  unsigned short* Vt  = (unsigned short*)(ws + (2u << 20));           // 1 MB bf16 [B][H][D][N]
  unsigned short* Ahi = (unsigned short*)(ws + (3u << 20));           // 1 MB bf16 [B*M][E]
  unsigned short* Alo = (unsigned short*)(ws + (4u << 20));           // 1 MB bf16 [B*M][E]
  unsigned short* Whi = (unsigned short*)(ws + (5u << 20));           // 128 KB
  unsigned short* Wlo = (unsigned short*)(ws + (5u << 20) + (1u << 17)); // 128 KB
  unsigned int*   cnt = (unsigned int*)(ws + (5u << 20) + (2u << 17));   // 256 B counters

  proj_all_kernel<<<dim3(64, 13), 256, 0, stream>>>(q_input, kv_input, Wq, Wkv, Wout,
                                                    Qs, Ks, Vt, Whi, Wlo, cnt);
  attn_kernel<<<dim3(1024), 256, 0, stream>>>(Qs, Ks, Vt, dmat, W1, b1, W2,
                                              Ahi, Alo, Whi, Wlo, out, cnt);
}

// Round 13
// 146.535 us; speedup vs baseline: 2.3295x; 1.1833x over previous
//
#include <hip/hip_runtime.h>
#include <stdint.h>
#include <stddef.h>

#define MM 512
#define NN 512
#define EE 256
#define HH 16
#define DD 16

typedef __bf16 bf16x8 __attribute__((ext_vector_type(8)));
typedef float f32x4 __attribute__((ext_vector_type(4)));

static __device__ __forceinline__ bf16x8 bzero8() {
  bf16x8 z;
#pragma unroll
  for (int i = 0; i < 8; ++i) z[i] = (__bf16)0.0f;
  return z;
}

static __device__ __forceinline__ bf16x8 cvt8(const float* __restrict__ p) {
  const float4 u = *(const float4*)p;
  const float4 v = *(const float4*)(p + 4);
  bf16x8 r;
  r[0] = (__bf16)u.x; r[1] = (__bf16)u.y; r[2] = (__bf16)u.z; r[3] = (__bf16)u.w;
  r[4] = (__bf16)v.x; r[5] = (__bf16)v.y; r[6] = (__bf16)v.z; r[7] = (__bf16)v.w;
  return r;
}

static __device__ __forceinline__ unsigned short f2b(float f) {
  union { __bf16 h; unsigned short u; } cv;
  cv.h = (__bf16)f;
  return cv.u;
}

static __device__ __forceinline__ float b2f(unsigned short u) {
  union { unsigned int i; float f; } cv;
  cv.i = ((unsigned int)u) << 16;
  return cv.f;
}

// raw v_exp_f32: computes 2^x (1/ln2 folded into MLP coefficients)
static __device__ __forceinline__ float fexp2(float x) {
  float r;
  asm("v_exp_f32 %0, %1" : "=v"(r) : "v"(x));
  return r;
}

// packed bf16 convert: dst.lo = bf16(lo), dst.hi = bf16(hi)
static __device__ __forceinline__ unsigned int cvtpk(float lo, float hi) {
  unsigned int r;
  asm("v_cvt_pk_bf16_f32 %0, %1, %2" : "=v"(r) : "v"(lo), "v"(hi));
  return r;
}

static __device__ __forceinline__ float sload(const float* p) {
  return __int_as_float(__builtin_amdgcn_readfirstlane(__float_as_int(*p)));
}

// ---------------------------------------------------------------------------
// Kernel 1: projections. by 0-3 -> Q, 4-11 -> KV, 12 -> Wout split + cnt zero
// ---------------------------------------------------------------------------
__global__ __launch_bounds__(256) void proj_all_kernel(
    const float* __restrict__ Xq, const float* __restrict__ Xkv,
    const float* __restrict__ Wq, const float* __restrict__ Wkv,
    const float* __restrict__ Wout,
    unsigned short* __restrict__ Qs, unsigned short* __restrict__ Ks,
    unsigned short* __restrict__ Vt,
    unsigned short* __restrict__ Whi, unsigned short* __restrict__ Wlo,
    unsigned int* __restrict__ cnt) {
  const int by = blockIdx.y;
  const int tid = threadIdx.x;

  if (by == 12) {
    if (blockIdx.x == 0 && tid < 64) cnt[tid] = 0u;  // tail counters, each call
    const int base = (blockIdx.x * 256 + tid) * 4;
    const float4 v = *(const float4*)(Wout + base);
    float c4[4] = {v.x, v.y, v.z, v.w};
#pragma unroll
    for (int i = 0; i < 4; ++i) {
      const unsigned short hb = f2b(c4[i]);
      Whi[base + i] = hb;
      Wlo[base + i] = f2b(c4[i] - b2f(hb));
    }
    return;
  }

  const int w = tid >> 6, l = tid & 63;
  const int lg = l >> 4, lr = l & 15;
  const int t0 = blockIdx.x * 32 + (w & 1) * 16;

  if (by < 4) {
    const int n0 = by * 64 + (w >> 1) * 32;
    f32x4 acc0 = {0.f, 0.f, 0.f, 0.f}, acc1 = {0.f, 0.f, 0.f, 0.f};
#pragma unroll
    for (int kc = 0; kc < EE; kc += 32) {
      const int k = kc + lg * 8;
      bf16x8 a  = cvt8(Xq + (size_t)(t0 + lr) * EE + k);
      bf16x8 b0 = cvt8(Wq + (size_t)(n0 + lr) * EE + k);
      bf16x8 b1 = cvt8(Wq + (size_t)(n0 + 16 + lr) * EE + k);
      acc0 = __builtin_amdgcn_mfma_f32_16x16x32_bf16(a, b0, acc0, 0, 0, 0);
      acc1 = __builtin_amdgcn_mfma_f32_16x16x32_bf16(a, b1, acc1, 0, 0, 0);
    }
#pragma unroll
    for (int r = 0; r < 4; ++r) {
      const int t = t0 + 4 * lg + r, b = t >> 9, m = t & 511;
      const int j0 = n0 + lr, j1 = j0 + 16;
      Qs[((size_t)(b * HH + (j0 >> 4)) * MM + m) * DD + (j0 & 15)] = f2b(acc0[r] * 0.25f);
      Qs[((size_t)(b * HH + (j1 >> 4)) * MM + m) * DD + (j1 & 15)] = f2b(acc1[r] * 0.25f);
    }
  } else {
    const int n0 = (by - 4) * 64 + (w >> 1) * 32;
    f32x4 acc0 = {0.f, 0.f, 0.f, 0.f}, acc1 = {0.f, 0.f, 0.f, 0.f};
#pragma unroll
    for (int kc = 0; kc < EE; kc += 32) {
      const int k = kc + lg * 8;
      bf16x8 a  = cvt8(Xkv + (size_t)(t0 + lr) * EE + k);
      bf16x8 b0 = cvt8(Wkv + (size_t)(n0 + lr) * EE + k);
      bf16x8 b1 = cvt8(Wkv + (size_t)(n0 + 16 + lr) * EE + k);
      acc0 = __builtin_amdgcn_mfma_f32_16x16x32_bf16(a, b0, acc0, 0, 0, 0);
      acc1 = __builtin_amdgcn_mfma_f32_16x16x32_bf16(a, b1, acc1, 0, 0, 0);
    }
#pragma unroll
    for (int r = 0; r < 4; ++r) {
      const int t = t0 + 4 * lg + r, b = t >> 9, n = t & 511;
#pragma unroll
      for (int fi = 0; fi < 2; ++fi) {
        const int j = n0 + lr + fi * 16;
        const float v = fi ? acc1[r] : acc0[r];
        if (j < 256) {
          Ks[((size_t)(b * HH + (j >> 4)) * NN + n) * DD + (j & 15)] = f2b(v);
        } else {
          const int jj = j - 256;
          Vt[((size_t)(b * HH + (jj >> 4)) * DD + (jj & 15)) * NN + n] = f2b(v);
        }
      }
    }
  }
}

// ---------------------------------------------------------------------------
// Kernel 2: fused attention + last-sibling out-GEMM tail.
// Round 13: (256,2) VGPR cap (round-12's (256,4) flipped allocator to 64 regs
// -> spill -> 157us); tail split into two 64-col passes with acc[4] (halves
// tail register pressure). Sibling-group XCD swizzle kept (FETCH 96->24MB).
// ---------------------------------------------------------------------------
__global__ __launch_bounds__(256, 2) void attn_kernel(
    const unsigned short* __restrict__ Qs, const unsigned short* __restrict__ Ks,
    const unsigned short* __restrict__ Vt, const float* __restrict__ dmat,
    const float* __restrict__ W1, const float* __restrict__ b1v,
    const float* __restrict__ W2,
    unsigned short* __restrict__ Ahi, unsigned short* __restrict__ Alo,
    const unsigned short* __restrict__ Whi, const unsigned short* __restrict__ Wlo,
    float* __restrict__ out, unsigned int* __restrict__ cnt) {
  __shared__ unsigned short P[32][520];   // bf16 probs; pvred aliased later
  __shared__ float red[4][32];            // per-wave row sums
  __shared__ int lastf;
  float (*pvred)[2][16][16] = (float (*)[2][16][16]) & P[0][0];  // 8KB alias

  const int tid = threadIdx.x, w = tid >> 6, l = tid & 63;
  const int lg = l >> 4, lr = l & 15;
  const int bid = blockIdx.x;
  // sibling-group XCD swizzle: group g=(b*16+mt) -> XCD g&7
  const int xcd = bid & 7, slot = bid >> 3;
  const int hh = slot & 15;
  const int g = (slot >> 4) * 8 + xcd;      // 0..63
  const int b = g >> 4, mt = g & 15;
  const int m0 = mt * 32;
  const int n0 = w * 128;

  const unsigned short* Qbase = Qs + ((size_t)(b * HH + hh) * MM + m0) * DD;
  const unsigned short* Kbase = Ks + (size_t)(b * HH + hh) * NN * DD;
  const unsigned short* Vbase = Vt + (size_t)(b * HH + hh) * DD * NN;
  const float* dbase = dmat + (size_t)b * MM * NN;

  // MLP coefficients. relu(x)=(x+|x|)/2, fold 0.5*W2 and 1/ln2 into wk;
  // wk|ak s + ck d + bk| = wkp*|s + ckp*d + bkp|. ckv/bkv pinned to VGPRs.
  float ckv[16], bkv[16], wkp[16];
  float Ac = 0.f, Cc = 0.f;
  const float hiln2 = 0.5f * 1.4426950408889634f;
#pragma unroll
  for (int k = 0; k < 16; ++k) {
    const float ak = sload(W1 + hh * 32 + k);
    const float ck = sload(W1 + hh * 32 + 16 + k);
    const float bk = sload(b1v + hh * 16 + k);
    const float wk = hiln2 * sload(W2 + hh * 16 + k);
    Ac += wk * ak;
    Cc += wk * ck;
    const float ra = 1.0f / ak;
    ckv[k] = ck * ra;
    bkv[k] = bk * ra;
    wkp[k] = wk * fabsf(ak);
    asm volatile("" : "+v"(ckv[k]));
    asm volatile("" : "+v"(bkv[k]));
  }

  bf16x8 qb[2];
#pragma unroll
  for (int mb = 0; mb < 2; ++mb) {
    qb[mb] = bzero8();
    if (lg < 2) qb[mb] = *(const bf16x8*)(Qbase + (mb * 16 + lr) * DD + lg * 8);
  }

  const f32x4 zf = {0.f, 0.f, 0.f, 0.f};
  float psum[2] = {0.f, 0.f};

  const float* dpl0 = dbase + (size_t)(m0 + lr) * NN + n0 + 4 * lg;
  const float* dpl1 = dbase + (size_t)(m0 + 16 + lr) * NN + n0 + 4 * lg;

  float4 dva0 = *(const float4*)(dpl0);
  float4 dva1 = *(const float4*)(dpl1);
  bf16x8 ka0 = bzero8();
  if (lg < 2) ka0 = *(const bf16x8*)(Kbase + (size_t)(n0 + lr) * DD + lg * 8);

#pragma unroll
  for (int nb = 0; nb < 8; ++nb) {
    float4 dvb0, dvb1;
    bf16x8 ka1 = bzero8();
    if (nb < 7) {
      dvb0 = *(const float4*)(dpl0 + (nb + 1) * 16);
      dvb1 = *(const float4*)(dpl1 + (nb + 1) * 16);
      if (lg < 2)
        ka1 = *(const bf16x8*)(Kbase + (size_t)(n0 + (nb + 1) * 16 + lr) * DD + lg * 8);
    }

    // swapped QK^T: C = S^T, row = n (4lg+r), col = m (lr)
    f32x4 cc[2];
    cc[0] = __builtin_amdgcn_mfma_f32_16x16x32_bf16(ka0, qb[0], zf, 0, 0, 0);
    cc[1] = __builtin_amdgcn_mfma_f32_16x16x32_bf16(ka0, qb[1], zf, 0, 0, 0);

#pragma unroll
    for (int mb = 0; mb < 2; ++mb) {
      const float4 dvv = mb ? dva1 : dva0;
      float ev[4];
#pragma unroll
      for (int r = 0; r < 4; ++r) {
        const float s = cc[mb][r];
        const float d = (r == 0) ? dvv.x : (r == 1) ? dvv.y : (r == 2) ? dvv.z : dvv.w;
        float acc = fmaf(Ac, s, Cc * d);
#pragma unroll
        for (int k = 0; k < 16; ++k) {
          const float t = fmaf(ckv[k], d, bkv[k]);
          acc = fmaf(wkp[k], fabsf(s + t), acc);
        }
        const float e = fexp2(acc);   // no max-subtraction: |mixed| bounded
        psum[mb] += e;
        ev[r] = e;
      }
      uint2 u;
      u.x = cvtpk(ev[0], ev[1]);
      u.y = cvtpk(ev[2], ev[3]);
      *(uint2*)&P[mb * 16 + lr][n0 + nb * 16 + 4 * lg] = u;
    }

    dva0 = dvb0;
    dva1 = dvb1;
    ka0 = ka1;
  }

#pragma unroll
  for (int mb = 0; mb < 2; ++mb) {
    psum[mb] += __shfl_xor(psum[mb], 16);
    psum[mb] += __shfl_xor(psum[mb], 32);
    if (lg == 0) red[w][mb * 16 + lr] = psum[mb];
  }

  // PV over this wave's own n-range (self-written P rows)
  f32x4 pv[2];
  pv[0] = zf; pv[1] = zf;
#pragma unroll
  for (int kb = 0; kb < 4; ++kb) {
    const bf16x8 vb = *(const bf16x8*)(Vbase + (size_t)lr * NN + (n0 + kb * 32 + lg * 8));
#pragma unroll
    for (int mb = 0; mb < 2; ++mb) {
      const bf16x8 pa = *(const bf16x8*)(&P[mb * 16 + lr][n0 + kb * 32 + lg * 8]);
      pv[mb] = __builtin_amdgcn_mfma_f32_16x16x32_bf16(pa, vb, pv[mb], 0, 0, 0);
    }
  }
  __syncthreads();   // all P reads complete before pvred aliases onto P
#pragma unroll
  for (int mb = 0; mb < 2; ++mb)
#pragma unroll
    for (int r = 0; r < 4; ++r) pvred[w][mb][4 * lg + r][lr] = pv[mb][r];
  __syncthreads();

  for (int i = tid; i < 512; i += 256) {
    const int mr = i >> 4, dd = i & 15;
    const float s = pvred[0][mr >> 4][mr & 15][dd] + pvred[1][mr >> 4][mr & 15][dd] +
                    pvred[2][mr >> 4][mr & 15][dd] + pvred[3][mr >> 4][mr & 15][dd];
    const float rs = red[0][mr] + red[1][mr] + red[2][mr] + red[3][mr];
    const float val = s / rs;
    const unsigned short hb = f2b(val);
    const size_t o = ((size_t)(b * MM) + m0 + mr) * EE + hh * DD + dd;
    Ahi[o] = hb;
    Alo[o] = f2b(val - b2f(hb));
  }

  // ---- last of the 16 head-siblings computes out = A @ Wout^T for (b,mt) ----
  if (tid == 0) {
    __threadfence();   // release this block's Ahi/Alo stores
    const unsigned int old = __hip_atomic_fetch_add(
        &cnt[g], 1u, __ATOMIC_ACQ_REL, __HIP_MEMORY_SCOPE_AGENT);
    lastf = (old == 15u) ? 1 : 0;
  }
  __syncthreads();
  if (lastf) {
    __threadfence();   // acquire side
    const int rbase = b * MM + m0 + (w & 1) * 16;   // wave: 16 rows
    // two sequential 64-col passes (acc[4] live -> low register pressure)
#pragma clang loop unroll(disable)
    for (int half = 0; half < 2; ++half) {
      const int c0 = (w >> 1) * 128 + half * 64;
      f32x4 acc[4] = {zf, zf, zf, zf};
#pragma unroll
      for (int kc = 0; kc < EE; kc += 32) {
        const int k = kc + lg * 8;
        const bf16x8 ah = *(const bf16x8*)(Ahi + (size_t)(rbase + lr) * EE + k);
        const bf16x8 al = *(const bf16x8*)(Alo + (size_t)(rbase + lr) * EE + k);
#pragma unroll
        for (int t = 0; t < 4; ++t) {
          const bf16x8 bh = *(const bf16x8*)(Whi + (size_t)(c0 + t * 16 + lr) * EE + k);
          const bf16x8 bl = *(const bf16x8*)(Wlo + (size_t)(c0 + t * 16 + lr) * EE + k);
          acc[t] = __builtin_amdgcn_mfma_f32_16x16x32_bf16(ah, bh, acc[t], 0, 0, 0);
          acc[t] = __builtin_amdgcn_mfma_f32_16x16x32_bf16(al, bh, acc[t], 0, 0, 0);
          acc[t] = __builtin_amdgcn_mfma_f32_16x16x32_bf16(ah, bl, acc[t], 0, 0, 0);
        }
      }
#pragma unroll
      for (int t = 0; t < 4; ++t)
#pragma unroll
        for (int r = 0; r < 4; ++r)
          out[(size_t)(rbase + 4 * lg + r) * EE + c0 + t * 16 + lr] = acc[t][r];
    }
  }
}

// ---------------------------------------------------------------------------
extern "C" void kernel_launch(void* const* d_in, const int* in_sizes, int n_in,
                              void* d_out, int out_size, void* d_ws, size_t ws_size,
                              hipStream_t stream) {
  const float* q_input  = (const float*)d_in[0];
  const float* kv_input = (const float*)d_in[1];
  const float* dmat     = (const float*)d_in[2];
  const float* Wq       = (const float*)d_in[3];
  const float* Wkv      = (const float*)d_in[4];
  const float* W1       = (const float*)d_in[5];
  const float* b1       = (const float*)d_in[6];
  const float* W2       = (const float*)d_in[7];
  // d_in[8] = mix_b2: no effect inside softmax, unused
  const float* Wout     = (const float*)d_in[9];
  float* out = (float*)d_out;

  char* ws = (char*)d_ws;
  unsigned short* Qs  = (unsigned short*)(ws);                        // 1 MB bf16 [B][H][M][D]
  unsigned short* Ks  = (unsigned short*)(ws + (1u << 20));           // 1 MB bf16 [B][H][N][D]
  unsigned short* Vt  = (unsigned short*)(ws + (2u << 20));           // 1 MB bf16 [B][H][D][N]
  unsigned short* Ahi = (unsigned short*)(ws + (3u << 20));           // 1 MB bf16 [B*M][E]
  unsigned short* Alo = (unsigned short*)(ws + (4u << 20));           // 1 MB bf16 [B*M][E]
  unsigned short* Whi = (unsigned short*)(ws + (5u << 20));           // 128 KB
  unsigned short* Wlo = (unsigned short*)(ws + (5u << 20) + (1u << 17)); // 128 KB
  unsigned int*   cnt = (unsigned int*)(ws + (5u << 20) + (2u << 17));   // 256 B counters

  proj_all_kernel<<<dim3(64, 13), 256, 0, stream>>>(q_input, kv_input, Wq, Wkv, Wout,
                                                    Qs, Ks, Vt, Whi, Wlo, cnt);
  attn_kernel<<<dim3(1024), 256, 0, stream>>>(Qs, Ks, Vt, dmat, W1, b1, W2,
                                              Ahi, Alo, Whi, Wlo, out, cnt);
}

// Round 14
// 61.702 us; speedup vs baseline: 5.5324x; 2.3749x over previous
//
#include <hip/hip_runtime.h>
#include <stdint.h>
#include <stddef.h>

#define MM 512
#define NN 512
#define EE 256
#define HH 16
#define DD 16

typedef __bf16 bf16x8 __attribute__((ext_vector_type(8)));
typedef float f32x4 __attribute__((ext_vector_type(4)));

static __device__ __forceinline__ bf16x8 bzero8() {
  bf16x8 z;
#pragma unroll
  for (int i = 0; i < 8; ++i) z[i] = (__bf16)0.0f;
  return z;
}

static __device__ __forceinline__ bf16x8 cvt8(const float* __restrict__ p) {
  const float4 u = *(const float4*)p;
  const float4 v = *(const float4*)(p + 4);
  bf16x8 r;
  r[0] = (__bf16)u.x; r[1] = (__bf16)u.y; r[2] = (__bf16)u.z; r[3] = (__bf16)u.w;
  r[4] = (__bf16)v.x; r[5] = (__bf16)v.y; r[6] = (__bf16)v.z; r[7] = (__bf16)v.w;
  return r;
}

static __device__ __forceinline__ unsigned short f2b(float f) {
  union { __bf16 h; unsigned short u; } cv;
  cv.h = (__bf16)f;
  return cv.u;
}

static __device__ __forceinline__ float b2f(unsigned short u) {
  union { unsigned int i; float f; } cv;
  cv.i = ((unsigned int)u) << 16;
  return cv.f;
}

static __device__ __forceinline__ float b2f_lo(unsigned int u) {
  return __int_as_float((int)(u << 16));
}
static __device__ __forceinline__ float b2f_hi(unsigned int u) {
  return __int_as_float((int)(u & 0xffff0000u));
}

// raw v_exp_f32: computes 2^x (1/ln2 folded into MLP coefficients)
static __device__ __forceinline__ float fexp2(float x) {
  float r;
  asm("v_exp_f32 %0, %1" : "=v"(r) : "v"(x));
  return r;
}

// packed bf16 convert: dst.lo = bf16(lo), dst.hi = bf16(hi)
static __device__ __forceinline__ unsigned int cvtpk(float lo, float hi) {
  unsigned int r;
  asm("v_cvt_pk_bf16_f32 %0, %1, %2" : "=v"(r) : "v"(lo), "v"(hi));
  return r;
}

static __device__ __forceinline__ float sload(const float* p) {
  return __int_as_float(__builtin_amdgcn_readfirstlane(__float_as_int(*p)));
}

// ---------------------------------------------------------------------------
// Kernel 1: projections. by 0-3 -> Q, 4-11 -> KV, 12 -> Wout split,
// 13 -> dmat fp32 -> bf16 copy (halves attn's dominant memory stream).
// ---------------------------------------------------------------------------
__global__ __launch_bounds__(256) void proj_all_kernel(
    const float* __restrict__ Xq, const float* __restrict__ Xkv,
    const float* __restrict__ Wq, const float* __restrict__ Wkv,
    const float* __restrict__ Wout, const float* __restrict__ dmat,
    unsigned short* __restrict__ Qs, unsigned short* __restrict__ Ks,
    unsigned short* __restrict__ Vt,
    unsigned short* __restrict__ Whi, unsigned short* __restrict__ Wlo,
    unsigned short* __restrict__ dmatb) {
  const int by = blockIdx.y;
  const int tid = threadIdx.x;

  if (by == 13) {
    // dmat -> bf16: 262144 float4s over 16384 threads, 16 coalesced passes
    const int base = blockIdx.x * 256 + tid;
#pragma unroll
    for (int it = 0; it < 16; ++it) {
      const int i4 = it * 16384 + base;
      const float4 v = *(const float4*)(dmat + (size_t)i4 * 4);
      uint2 u;
      u.x = cvtpk(v.x, v.y);
      u.y = cvtpk(v.z, v.w);
      *(uint2*)(dmatb + (size_t)i4 * 4) = u;
    }
    return;
  }

  if (by == 12) {
    const int base = (blockIdx.x * 256 + tid) * 4;
    const float4 v = *(const float4*)(Wout + base);
    float c4[4] = {v.x, v.y, v.z, v.w};
#pragma unroll
    for (int i = 0; i < 4; ++i) {
      const unsigned short hb = f2b(c4[i]);
      Whi[base + i] = hb;
      Wlo[base + i] = f2b(c4[i] - b2f(hb));
    }
    return;
  }

  const int w = tid >> 6, l = tid & 63;
  const int lg = l >> 4, lr = l & 15;
  const int t0 = blockIdx.x * 32 + (w & 1) * 16;

  if (by < 4) {
    const int n0 = by * 64 + (w >> 1) * 32;
    f32x4 acc0 = {0.f, 0.f, 0.f, 0.f}, acc1 = {0.f, 0.f, 0.f, 0.f};
#pragma unroll
    for (int kc = 0; kc < EE; kc += 32) {
      const int k = kc + lg * 8;
      bf16x8 a  = cvt8(Xq + (size_t)(t0 + lr) * EE + k);
      bf16x8 b0 = cvt8(Wq + (size_t)(n0 + lr) * EE + k);
      bf16x8 b1 = cvt8(Wq + (size_t)(n0 + 16 + lr) * EE + k);
      acc0 = __builtin_amdgcn_mfma_f32_16x16x32_bf16(a, b0, acc0, 0, 0, 0);
      acc1 = __builtin_amdgcn_mfma_f32_16x16x32_bf16(a, b1, acc1, 0, 0, 0);
    }
#pragma unroll
    for (int r = 0; r < 4; ++r) {
      const int t = t0 + 4 * lg + r, b = t >> 9, m = t & 511;
      const int j0 = n0 + lr, j1 = j0 + 16;
      Qs[((size_t)(b * HH + (j0 >> 4)) * MM + m) * DD + (j0 & 15)] = f2b(acc0[r] * 0.25f);
      Qs[((size_t)(b * HH + (j1 >> 4)) * MM + m) * DD + (j1 & 15)] = f2b(acc1[r] * 0.25f);
    }
  } else {
    const int n0 = (by - 4) * 64 + (w >> 1) * 32;
    f32x4 acc0 = {0.f, 0.f, 0.f, 0.f}, acc1 = {0.f, 0.f, 0.f, 0.f};
#pragma unroll
    for (int kc = 0; kc < EE; kc += 32) {
      const int k = kc + lg * 8;
      bf16x8 a  = cvt8(Xkv + (size_t)(t0 + lr) * EE + k);
      bf16x8 b0 = cvt8(Wkv + (size_t)(n0 + lr) * EE + k);
      bf16x8 b1 = cvt8(Wkv + (size_t)(n0 + 16 + lr) * EE + k);
      acc0 = __builtin_amdgcn_mfma_f32_16x16x32_bf16(a, b0, acc0, 0, 0, 0);
      acc1 = __builtin_amdgcn_mfma_f32_16x16x32_bf16(a, b1, acc1, 0, 0, 0);
    }
#pragma unroll
    for (int r = 0; r < 4; ++r) {
      const int t = t0 + 4 * lg + r, b = t >> 9, n = t & 511;
#pragma unroll
      for (int fi = 0; fi < 2; ++fi) {
        const int j = n0 + lr + fi * 16;
        const float v = fi ? acc1[r] : acc0[r];
        if (j < 256) {
          Ks[((size_t)(b * HH + (j >> 4)) * NN + n) * DD + (j & 15)] = f2b(v);
        } else {
          const int jj = j - 256;
          Vt[((size_t)(b * HH + (jj >> 4)) * DD + (jj & 15)) * NN + n] = f2b(v);
        }
      }
    }
  }
}

// ---------------------------------------------------------------------------
// Kernel 2: fused attention (round-10/13 main body; NO tail, NO fences).
// Sibling-group XCD swizzle (FETCH 96->13MB proven); bf16 dmat (halved bytes).
// (256,2) bounds: proven VGPR~80, no spill.
// ---------------------------------------------------------------------------
__global__ __launch_bounds__(256, 2) void attn_kernel(
    const unsigned short* __restrict__ Qs, const unsigned short* __restrict__ Ks,
    const unsigned short* __restrict__ Vt, const unsigned short* __restrict__ dmatb,
    const float* __restrict__ W1, const float* __restrict__ b1v,
    const float* __restrict__ W2,
    unsigned short* __restrict__ Ahi, unsigned short* __restrict__ Alo) {
  __shared__ unsigned short P[32][520];   // bf16 probs; pvred aliased later
  __shared__ float red[4][32];            // per-wave row sums
  float (*pvred)[2][16][16] = (float (*)[2][16][16]) & P[0][0];  // 8KB alias

  const int tid = threadIdx.x, w = tid >> 6, l = tid & 63;
  const int lg = l >> 4, lr = l & 15;
  const int bid = blockIdx.x;
  // sibling-group XCD swizzle: group g=(b*16+mt) -> XCD g&7
  const int xcd = bid & 7, slot = bid >> 3;
  const int hh = slot & 15;
  const int g = (slot >> 4) * 8 + xcd;      // 0..63
  const int b = g >> 4, mt = g & 15;
  const int m0 = mt * 32;
  const int n0 = w * 128;

  const unsigned short* Qbase = Qs + ((size_t)(b * HH + hh) * MM + m0) * DD;
  const unsigned short* Kbase = Ks + (size_t)(b * HH + hh) * NN * DD;
  const unsigned short* Vbase = Vt + (size_t)(b * HH + hh) * DD * NN;
  const unsigned short* dbase = dmatb + (size_t)b * MM * NN;

  // MLP coefficients. relu(x)=(x+|x|)/2, fold 0.5*W2 and 1/ln2 into wk;
  // wk|ak s + ck d + bk| = wkp*|s + ckp*d + bkp|. ckv/bkv pinned to VGPRs;
  // wkp/Ac/Cc uniform SGPR (1 SGPR per VALU instr is free).
  float ckv[16], bkv[16], wkp[16];
  float Ac = 0.f, Cc = 0.f;
  const float hiln2 = 0.5f * 1.4426950408889634f;
#pragma unroll
  for (int k = 0; k < 16; ++k) {
    const float ak = sload(W1 + hh * 32 + k);
    const float ck = sload(W1 + hh * 32 + 16 + k);
    const float bk = sload(b1v + hh * 16 + k);
    const float wk = hiln2 * sload(W2 + hh * 16 + k);
    Ac += wk * ak;
    Cc += wk * ck;
    const float ra = 1.0f / ak;
    ckv[k] = ck * ra;
    bkv[k] = bk * ra;
    wkp[k] = wk * fabsf(ak);
    asm volatile("" : "+v"(ckv[k]));   // pin to VGPR
    asm volatile("" : "+v"(bkv[k]));   // pin to VGPR
  }

  bf16x8 qb[2];
#pragma unroll
  for (int mb = 0; mb < 2; ++mb) {
    qb[mb] = bzero8();
    if (lg < 2) qb[mb] = *(const bf16x8*)(Qbase + (mb * 16 + lr) * DD + lg * 8);
  }

  const f32x4 zf = {0.f, 0.f, 0.f, 0.f};
  float psum[2] = {0.f, 0.f};

  // bf16 dmat: lane covers (m0+mb*16+lr, n0+nb*16+4lg..+3) -> uint2 (8B)
  const unsigned short* dpl0 = dbase + (size_t)(m0 + lr) * NN + n0 + 4 * lg;
  const unsigned short* dpl1 = dbase + (size_t)(m0 + 16 + lr) * NN + n0 + 4 * lg;

  // software prefetch: dmat uint2 pair + K fragment, 1 nb ahead
  uint2 dva0 = *(const uint2*)(dpl0);
  uint2 dva1 = *(const uint2*)(dpl1);
  bf16x8 ka0 = bzero8();
  if (lg < 2) ka0 = *(const bf16x8*)(Kbase + (size_t)(n0 + lr) * DD + lg * 8);

#pragma unroll
  for (int nb = 0; nb < 8; ++nb) {
    uint2 dvb0, dvb1;
    bf16x8 ka1 = bzero8();
    if (nb < 7) {
      dvb0 = *(const uint2*)(dpl0 + (nb + 1) * 16);
      dvb1 = *(const uint2*)(dpl1 + (nb + 1) * 16);
      if (lg < 2)
        ka1 = *(const bf16x8*)(Kbase + (size_t)(n0 + (nb + 1) * 16 + lr) * DD + lg * 8);
    }

    // swapped QK^T: C = S^T, row = n (4lg+r), col = m (lr)
    f32x4 cc[2];
    cc[0] = __builtin_amdgcn_mfma_f32_16x16x32_bf16(ka0, qb[0], zf, 0, 0, 0);
    cc[1] = __builtin_amdgcn_mfma_f32_16x16x32_bf16(ka0, qb[1], zf, 0, 0, 0);

#pragma unroll
    for (int mb = 0; mb < 2; ++mb) {
      const uint2 dvv = mb ? dva1 : dva0;
      float dunp[4];
      dunp[0] = b2f_lo(dvv.x);
      dunp[1] = b2f_hi(dvv.x);
      dunp[2] = b2f_lo(dvv.y);
      dunp[3] = b2f_hi(dvv.y);
      float ev[4];
#pragma unroll
      for (int r = 0; r < 4; ++r) {
        const float s = cc[mb][r];
        const float d = dunp[r];
        float acc = fmaf(Ac, s, Cc * d);
#pragma unroll
        for (int k = 0; k < 16; ++k) {
          const float t = fmaf(ckv[k], d, bkv[k]);   // all-VGPR fma
          acc = fmaf(wkp[k], fabsf(s + t), acc);     // SGPR coeff + abs modifier
        }
        const float e = fexp2(acc);   // no max-subtraction: |mixed| bounded
        psum[mb] += e;
        ev[r] = e;
      }
      uint2 u;
      u.x = cvtpk(ev[0], ev[1]);
      u.y = cvtpk(ev[2], ev[3]);
      *(uint2*)&P[mb * 16 + lr][n0 + nb * 16 + 4 * lg] = u;
    }

    dva0 = dvb0;
    dva1 = dvb1;
    ka0 = ka1;
  }

#pragma unroll
  for (int mb = 0; mb < 2; ++mb) {
    psum[mb] += __shfl_xor(psum[mb], 16);
    psum[mb] += __shfl_xor(psum[mb], 32);
    if (lg == 0) red[w][mb * 16 + lr] = psum[mb];
  }

  // PV over this wave's own n-range (self-written P rows)
  f32x4 pv[2];
  pv[0] = zf; pv[1] = zf;
#pragma unroll
  for (int kb = 0; kb < 4; ++kb) {
    const bf16x8 vb = *(const bf16x8*)(Vbase + (size_t)lr * NN + (n0 + kb * 32 + lg * 8));
#pragma unroll
    for (int mb = 0; mb < 2; ++mb) {
      const bf16x8 pa = *(const bf16x8*)(&P[mb * 16 + lr][n0 + kb * 32 + lg * 8]);
      pv[mb] = __builtin_amdgcn_mfma_f32_16x16x32_bf16(pa, vb, pv[mb], 0, 0, 0);
    }
  }
  __syncthreads();   // all P reads complete before pvred aliases onto P
#pragma unroll
  for (int mb = 0; mb < 2; ++mb)
#pragma unroll
    for (int r = 0; r < 4; ++r) pvred[w][mb][4 * lg + r][lr] = pv[mb][r];
  __syncthreads();

  for (int i = tid; i < 512; i += 256) {
    const int mr = i >> 4, dd = i & 15;
    const float s = pvred[0][mr >> 4][mr & 15][dd] + pvred[1][mr >> 4][mr & 15][dd] +
                    pvred[2][mr >> 4][mr & 15][dd] + pvred[3][mr >> 4][mr & 15][dd];
    const float rs = red[0][mr] + red[1][mr] + red[2][mr] + red[3][mr];
    const float val = s / rs;
    const unsigned short hb = f2b(val);
    const size_t o = ((size_t)(b * MM) + m0 + mr) * EE + hh * DD + dd;
    Ahi[o] = hb;
    Alo[o] = f2b(val - b2f(hb));
  }
}

// ---------------------------------------------------------------------------
// Kernel 3: out = Ahi@Whi^T + Alo@Whi^T + Ahi@Wlo^T (round-2 structure)
// ---------------------------------------------------------------------------
__global__ __launch_bounds__(256) void out_gemm_kernel(
    const unsigned short* __restrict__ Ahi, const unsigned short* __restrict__ Alo,
    const unsigned short* __restrict__ Whi, const unsigned short* __restrict__ Wlo,
    float* __restrict__ out) {
  const int tid = threadIdx.x, w = tid >> 6, l = tid & 63;
  const int lg = l >> 4, lr = l & 15;
  const int t0 = blockIdx.x * 32 + (w & 1) * 16;
  const int n0 = blockIdx.y * 64 + (w >> 1) * 32;
  f32x4 acc0 = {0.f, 0.f, 0.f, 0.f}, acc1 = {0.f, 0.f, 0.f, 0.f};
#pragma unroll
  for (int kc = 0; kc < EE; kc += 32) {
    const int k = kc + lg * 8;
    const bf16x8 ah = *(const bf16x8*)(Ahi + (size_t)(t0 + lr) * EE + k);
    const bf16x8 al = *(const bf16x8*)(Alo + (size_t)(t0 + lr) * EE + k);
    const bf16x8 bh0 = *(const bf16x8*)(Whi + (size_t)(n0 + lr) * EE + k);
    const bf16x8 bh1 = *(const bf16x8*)(Whi + (size_t)(n0 + 16 + lr) * EE + k);
    const bf16x8 bl0 = *(const bf16x8*)(Wlo + (size_t)(n0 + lr) * EE + k);
    const bf16x8 bl1 = *(const bf16x8*)(Wlo + (size_t)(n0 + 16 + lr) * EE + k);
    acc0 = __builtin_amdgcn_mfma_f32_16x16x32_bf16(ah, bh0, acc0, 0, 0, 0);
    acc0 = __builtin_amdgcn_mfma_f32_16x16x32_bf16(al, bh0, acc0, 0, 0, 0);
    acc0 = __builtin_amdgcn_mfma_f32_16x16x32_bf16(ah, bl0, acc0, 0, 0, 0);
    acc1 = __builtin_amdgcn_mfma_f32_16x16x32_bf16(ah, bh1, acc1, 0, 0, 0);
    acc1 = __builtin_amdgcn_mfma_f32_16x16x32_bf16(al, bh1, acc1, 0, 0, 0);
    acc1 = __builtin_amdgcn_mfma_f32_16x16x32_bf16(ah, bl1, acc1, 0, 0, 0);
  }
#pragma unroll
  for (int r = 0; r < 4; ++r) {
    const int row = t0 + 4 * lg + r;
    out[(size_t)row * EE + n0 + lr] = acc0[r];
    out[(size_t)row * EE + n0 + 16 + lr] = acc1[r];
  }
}

// ---------------------------------------------------------------------------
extern "C" void kernel_launch(void* const* d_in, const int* in_sizes, int n_in,
                              void* d_out, int out_size, void* d_ws, size_t ws_size,
                              hipStream_t stream) {
  const float* q_input  = (const float*)d_in[0];
  const float* kv_input = (const float*)d_in[1];
  const float* dmat     = (const float*)d_in[2];
  const float* Wq       = (const float*)d_in[3];
  const float* Wkv      = (const float*)d_in[4];
  const float* W1       = (const float*)d_in[5];
  const float* b1       = (const float*)d_in[6];
  const float* W2       = (const float*)d_in[7];
  // d_in[8] = mix_b2: no effect inside softmax, unused
  const float* Wout     = (const float*)d_in[9];
  float* out = (float*)d_out;

  char* ws = (char*)d_ws;
  unsigned short* Qs    = (unsigned short*)(ws);                        // 1 MB bf16 [B][H][M][D]
  unsigned short* Ks    = (unsigned short*)(ws + (1u << 20));           // 1 MB bf16 [B][H][N][D]
  unsigned short* Vt    = (unsigned short*)(ws + (2u << 20));           // 1 MB bf16 [B][H][D][N]
  unsigned short* Ahi   = (unsigned short*)(ws + (3u << 20));           // 1 MB bf16 [B*M][E]
  unsigned short* Alo   = (unsigned short*)(ws + (4u << 20));           // 1 MB bf16 [B*M][E]
  unsigned short* Whi   = (unsigned short*)(ws + (5u << 20));           // 128 KB
  unsigned short* Wlo   = (unsigned short*)(ws + (5u << 20) + (1u << 17)); // 128 KB
  unsigned short* dmatb = (unsigned short*)(ws + (6u << 20));           // 2 MB bf16 [B][M][N]

  proj_all_kernel<<<dim3(64, 14), 256, 0, stream>>>(q_input, kv_input, Wq, Wkv, Wout,
                                                    dmat, Qs, Ks, Vt, Whi, Wlo, dmatb);
  attn_kernel<<<dim3(1024), 256, 0, stream>>>(Qs, Ks, Vt, dmatb, W1, b1, W2,
                                              Ahi, Alo);
  out_gemm_kernel<<<dim3(64, 4), 256, 0, stream>>>(Ahi, Alo, Whi, Wlo, out);
}